// Round 1
// baseline (767.914 us; speedup 1.0000x reference)
//
#include <hip/hip_runtime.h>
#include <math.h>

// Problem constants (reference: N_CENTER=4000, N_NEIGH=16, N_FEAT=64)
#define NNEI   16
#define NFEAT  64
#define NPAIR  240              // 16*15 off-diagonal pairs
#define ROWW   195              // 1 + 1 + 1 + 64 + 64 + 64
#define PER_C  (NPAIR * ROWW)   // 46800 floats per center
#define COS_EPS 1e-8f

// LDS layout (flat, floats):
//   [0   .. 255 ]  ang[j*16+k]
//   [256 .. 271 ]  d[n]
//   [272 .. 335 ]  emb_i[f]
//   [336 .. 1359]  embd[n*64+f] = emb(neighbor n)[f] / d[n]
__global__ __launch_bounds__(256) void angdesc_kernel(
    const int*   __restrict__ atom_i_idx,
    const int*   __restrict__ atom_j_idx,
    const float* __restrict__ dist_ij,
    const float* __restrict__ atoms_xyz,
    const int*   __restrict__ atoms_long,
    const float* __restrict__ embed_table,
    float*       __restrict__ out0,   // (C,)       atom_i_idx as float
    float*       __restrict__ out1)   // (C,240,195)
{
    __shared__ float s_lds[1360];
    __shared__ float s_vec[NNEI][3];
    __shared__ float s_nrm[NNEI];
    __shared__ float s_invd[NNEI];
    __shared__ int   s_spec[NNEI];

    const int c   = blockIdx.x;
    const int tid = threadIdx.x;
    const int ii  = atom_i_idx[c];          // wave-uniform -> s_load

    if (tid == 0) out0[c] = (float)ii;

    const float xi = atoms_xyz[ii * 3 + 0];
    const float yi = atoms_xyz[ii * 3 + 1];
    const float zi = atoms_xyz[ii * 3 + 2];

    if (tid < NNEI) {
        const int jn = atom_j_idx[c * NNEI + tid];
        const float vx = atoms_xyz[jn * 3 + 0] - xi;
        const float vy = atoms_xyz[jn * 3 + 1] - yi;
        const float vz = atoms_xyz[jn * 3 + 2] - zi;
        s_vec[tid][0] = vx; s_vec[tid][1] = vy; s_vec[tid][2] = vz;
        s_nrm[tid]  = sqrtf(vx * vx + vy * vy + vz * vz);
        const float d = dist_ij[c * NNEI + tid];
        s_lds[256 + tid] = d;
        s_invd[tid] = 1.0f / d;
        s_spec[tid] = atoms_long[jn * 2 + 1];
    } else if (tid >= 64 && tid < 128) {
        const int f = tid - 64;
        const int speci = atoms_long[ii * 2 + 1];     // uniform
        s_lds[272 + f] = embed_table[speci * NFEAT + f];
    }
    __syncthreads();

    // Angle for every (j,k) in 16x16 (diagonal computed but never read).
    {
        const int j = tid >> 4, k = tid & 15;
        const float dot = s_vec[j][0] * s_vec[k][0]
                        + s_vec[j][1] * s_vec[k][1]
                        + s_vec[j][2] * s_vec[k][2];
        const float nj = fmaxf(s_nrm[j], COS_EPS);
        const float nk = fmaxf(s_nrm[k], COS_EPS);
        const float cosv = dot / (nj * nk);
        s_lds[tid] = acosf(cosv * 0.9999f);
    }
    // embd[n][f] = embed_table[spec[n]][f] / d[n]
    for (int e = tid; e < NNEI * NFEAT; e += 256) {
        const int n = e >> 6, f = e & 63;
        s_lds[336 + e] = embed_table[s_spec[n] * NFEAT + f] * s_invd[n];
    }
    __syncthreads();

    // Branch-free streaming write: one LDS gather + one coalesced store per elem.
    float* __restrict__ dst = out1 + (size_t)c * PER_C;
    for (int t = tid; t < PER_C; t += 256) {
        const unsigned p = (unsigned)t / 195u;         // pair index (magic mul)
        const int s = t - (int)p * 195;                // slot in row
        const unsigned ju = p / 15u;
        const int j = (int)ju;
        const int r = (int)(p - ju * 15u);
        const int k = r + (r >= j);
        const int off =
              (s >= 131) ? (336 + (k << 6) + (s - 131))   // emb_k / d_ik
            : (s >= 67)  ? (336 + (j << 6) + (s - 67))    // emb_j / d_ij
            : (s >= 3)   ? (269 + s)                      // emb_i
            : (s == 2)   ? ((j << 4) + k)                 // ang
            : (s == 1)   ? (256 + k)                      // d_ik
                         : (256 + j);                     // d_ij
        dst[t] = s_lds[off];
    }
}

extern "C" void kernel_launch(void* const* d_in, const int* in_sizes, int n_in,
                              void* d_out, int out_size, void* d_ws, size_t ws_size,
                              hipStream_t stream) {
    // setup_inputs order: [0]=nNeigh, [1]=atom_i_idx, [2]=atom_j_idx,
    // [3]=dist_ij, [4]=atoms_xyz, [5]=atoms_long, [6]=embed_table
    const int*   atom_i_idx  = (const int*)  d_in[1];
    const int*   atom_j_idx  = (const int*)  d_in[2];
    const float* dist_ij     = (const float*)d_in[3];
    const float* atoms_xyz   = (const float*)d_in[4];
    const int*   atoms_long  = (const int*)  d_in[5];
    const float* embed_table = (const float*)d_in[6];

    const int C = in_sizes[1];              // 4000 centers
    float* out  = (float*)d_out;

    angdesc_kernel<<<C, 256, 0, stream>>>(atom_i_idx, atom_j_idx, dist_ij,
                                          atoms_xyz, atoms_long, embed_table,
                                          out, out + C);
}

// Round 2
// 752.802 us; speedup vs baseline: 1.0201x; 1.0201x over previous
//
#include <hip/hip_runtime.h>
#include <math.h>

// Problem constants (reference: N_CENTER=4000, N_NEIGH=16, N_FEAT=64)
#define NNEI   16
#define NFEAT  64
#define NPAIR  240              // 16*15 off-diagonal pairs
#define ROWW   195              // 1 + 1 + 1 + 64 + 64 + 64
#define PER_C  (NPAIR * ROWW)   // 46800 floats per center
#define COS_EPS 1e-8f

// LDS value layout (flat, floats):
//   [0   .. 255 ]  ang[j*16+k]
//   [256 .. 271 ]  d[n]
//   [272 .. 335 ]  emb_i[f]
//   [336 .. 1359]  embd[n*64+f] = emb(neighbor n)[f] / d[n]

// The flat-element -> LDS-offset map is identical for all centers.
// Build it once per launch into d_ws as u16 (offsets < 1360 < 65536).
__global__ __launch_bounds__(256) void build_offtable(unsigned short* __restrict__ tab) {
    const int t = blockIdx.x * 256 + threadIdx.x;
    if (t >= PER_C) return;
    const unsigned p = (unsigned)t / 195u;         // pair index
    const int s = t - (int)p * 195;                // slot in row
    const unsigned ju = p / 15u;
    const int j = (int)ju;
    const int r = (int)(p - ju * 15u);
    const int k = r + (r >= j);
    const int off =
          (s >= 131) ? (336 + (k << 6) + (s - 131))   // emb_k / d_ik
        : (s >= 67)  ? (336 + (j << 6) + (s - 67))    // emb_j / d_ij
        : (s >= 3)   ? (269 + s)                      // emb_i
        : (s == 2)   ? ((j << 4) + k)                 // ang
        : (s == 1)   ? (256 + k)                      // d_ik
                     : (256 + j);                     // d_ij
    tab[t] = (unsigned short)off;
}

__global__ __launch_bounds__(256) void angdesc_kernel(
    const int*   __restrict__ atom_i_idx,
    const int*   __restrict__ atom_j_idx,
    const float* __restrict__ dist_ij,
    const float* __restrict__ atoms_xyz,
    const int*   __restrict__ atoms_long,
    const float* __restrict__ embed_table,
    const unsigned short* __restrict__ tab,   // 46800 u16 LDS offsets
    float*       __restrict__ out0,   // (C,)       atom_i_idx as float
    float*       __restrict__ out1)   // (C,240,195)
{
    __shared__ float s_lds[1360];
    __shared__ float s_vec[NNEI][3];
    __shared__ float s_nrm[NNEI];
    __shared__ float s_invd[NNEI];
    __shared__ int   s_spec[NNEI];

    const int c   = blockIdx.x;
    const int tid = threadIdx.x;
    const int ii  = atom_i_idx[c];          // wave-uniform -> s_load

    if (tid == 0) out0[c] = (float)ii;

    const float xi = atoms_xyz[ii * 3 + 0];
    const float yi = atoms_xyz[ii * 3 + 1];
    const float zi = atoms_xyz[ii * 3 + 2];

    if (tid < NNEI) {
        const int jn = atom_j_idx[c * NNEI + tid];
        const float vx = atoms_xyz[jn * 3 + 0] - xi;
        const float vy = atoms_xyz[jn * 3 + 1] - yi;
        const float vz = atoms_xyz[jn * 3 + 2] - zi;
        s_vec[tid][0] = vx; s_vec[tid][1] = vy; s_vec[tid][2] = vz;
        s_nrm[tid]  = sqrtf(vx * vx + vy * vy + vz * vz);
        const float d = dist_ij[c * NNEI + tid];
        s_lds[256 + tid] = d;
        s_invd[tid] = 1.0f / d;
        s_spec[tid] = atoms_long[jn * 2 + 1];
    } else if (tid >= 64 && tid < 128) {
        const int f = tid - 64;
        const int speci = atoms_long[ii * 2 + 1];     // uniform
        s_lds[272 + f] = embed_table[speci * NFEAT + f];
    }
    __syncthreads();

    // Angle for every (j,k) in 16x16 (diagonal computed but never read).
    {
        const int j = tid >> 4, k = tid & 15;
        const float dot = s_vec[j][0] * s_vec[k][0]
                        + s_vec[j][1] * s_vec[k][1]
                        + s_vec[j][2] * s_vec[k][2];
        const float nj = fmaxf(s_nrm[j], COS_EPS);
        const float nk = fmaxf(s_nrm[k], COS_EPS);
        const float cosv = dot / (nj * nk);
        s_lds[tid] = acosf(cosv * 0.9999f);
    }
    // embd[n][f] = embed_table[spec[n]][f] / d[n]
    for (int e = tid; e < NNEI * NFEAT; e += 256) {
        const int n = e >> 6, f = e & 63;
        s_lds[336 + e] = embed_table[s_spec[n] * NFEAT + f] * s_invd[n];
    }
    __syncthreads();

    // Store-bound streaming loop: per lane, 8B table load (L2-hot) +
    // 4x ds_read_b32 + 1x global_store_dwordx4.
    float4* __restrict__ dst4 = (float4*)(out1 + (size_t)c * PER_C);
    const ushort4* __restrict__ tab4 = (const ushort4*)tab;
    for (int q = tid; q < PER_C / 4; q += 256) {
        const ushort4 o = tab4[q];
        float4 v;
        v.x = s_lds[o.x];
        v.y = s_lds[o.y];
        v.z = s_lds[o.z];
        v.w = s_lds[o.w];
        dst4[q] = v;
    }
}

extern "C" void kernel_launch(void* const* d_in, const int* in_sizes, int n_in,
                              void* d_out, int out_size, void* d_ws, size_t ws_size,
                              hipStream_t stream) {
    // setup_inputs order: [0]=nNeigh, [1]=atom_i_idx, [2]=atom_j_idx,
    // [3]=dist_ij, [4]=atoms_xyz, [5]=atoms_long, [6]=embed_table
    const int*   atom_i_idx  = (const int*)  d_in[1];
    const int*   atom_j_idx  = (const int*)  d_in[2];
    const float* dist_ij     = (const float*)d_in[3];
    const float* atoms_xyz   = (const float*)d_in[4];
    const int*   atoms_long  = (const int*)  d_in[5];
    const float* embed_table = (const float*)d_in[6];

    const int C = in_sizes[1];              // 4000 centers
    float* out  = (float*)d_out;
    unsigned short* tab = (unsigned short*)d_ws;   // 46800 * 2 B = 93.6 KB

    build_offtable<<<(PER_C + 255) / 256, 256, 0, stream>>>(tab);
    angdesc_kernel<<<C, 256, 0, stream>>>(atom_i_idx, atom_j_idx, dist_ij,
                                          atoms_xyz, atoms_long, embed_table,
                                          tab, out, out + C);
}